// Round 1
// baseline (4623.312 us; speedup 1.0000x reference)
//
#include <hip/hip_runtime.h>
#include <hip/hip_bf16.h>

#define NN 16384
#define NE 524288
#define FIN 512
#define HD 256
#define HD2 128

// ---------------- degree / normalization ----------------
__global__ __launch_bounds__(256) void count_deg_kernel(const int* __restrict__ col,
                                                        float* __restrict__ deg, int E) {
    int e = blockIdx.x * blockDim.x + threadIdx.x;
    if (e < E) atomicAdd(&deg[col[e]], 1.0f);
}

__global__ __launch_bounds__(256) void finish_dis_kernel(float* __restrict__ deg, int n) {
    int i = blockIdx.x * blockDim.x + threadIdx.x;
    if (i < n) deg[i] = rsqrtf(deg[i] + 1.0f);  // +1 for self-loop; deg>=1 always
}

// ---------------- build concatenated [W1 | W2] ----------------
__global__ __launch_bounds__(256) void build_wcat_kernel(const float* __restrict__ W1,
                                                         const float* __restrict__ W2,
                                                         float* __restrict__ Wcat) {
    int t = blockIdx.x * blockDim.x + threadIdx.x;  // HD*HD
    int k = t / HD, j = t % HD;
    Wcat[t] = (j < HD2) ? W1[k * HD2 + j] : W2[k * HD2 + (j - HD2)];
}

// ---------------- generic fp32 tiled GEMM: C[M,Nc] = A[M,K] @ B[K,Nc] ----------------
// BM=BN=64, BK=16, 256 threads, 4x4 per thread. M,Nc % 64 == 0, K % 16 == 0.
__global__ __launch_bounds__(256) void gemm_f32_kernel(const float* __restrict__ A,
                                                       const float* __restrict__ B,
                                                       float* __restrict__ C,
                                                       int M, int Nc, int K) {
    __shared__ float As[16][68];  // transposed A tile: As[k][m]
    __shared__ float Bs[16][68];  // Bs[k][n]
    const int tid = threadIdx.x;
    const int tx = tid & 15, ty = tid >> 4;
    const int row0 = blockIdx.y * 64, col0 = blockIdx.x * 64;
    const int am = tid >> 2, ak4 = (tid & 3) << 2;
    const int bk = tid >> 4, bn4 = (tid & 15) << 2;
    float acc[4][4] = {};
    for (int k0 = 0; k0 < K; k0 += 16) {
        float4 va = *(const float4*)&A[(size_t)(row0 + am) * K + k0 + ak4];
        As[ak4 + 0][am] = va.x;
        As[ak4 + 1][am] = va.y;
        As[ak4 + 2][am] = va.z;
        As[ak4 + 3][am] = va.w;
        *(float4*)&Bs[bk][bn4] = *(const float4*)&B[(size_t)(k0 + bk) * Nc + col0 + bn4];
        __syncthreads();
#pragma unroll
        for (int k = 0; k < 16; ++k) {
            const float4 av = *(const float4*)&As[k][ty << 2];
            const float4 bv = *(const float4*)&Bs[k][tx << 2];
            const float a0 = av.x, a1 = av.y, a2 = av.z, a3 = av.w;
            const float c0 = bv.x, c1 = bv.y, c2 = bv.z, c3 = bv.w;
            acc[0][0] += a0 * c0; acc[0][1] += a0 * c1; acc[0][2] += a0 * c2; acc[0][3] += a0 * c3;
            acc[1][0] += a1 * c0; acc[1][1] += a1 * c1; acc[1][2] += a1 * c2; acc[1][3] += a1 * c3;
            acc[2][0] += a2 * c0; acc[2][1] += a2 * c1; acc[2][2] += a2 * c2; acc[2][3] += a2 * c3;
            acc[3][0] += a3 * c0; acc[3][1] += a3 * c1; acc[3][2] += a3 * c2; acc[3][3] += a3 * c3;
        }
        __syncthreads();
    }
#pragma unroll
    for (int i = 0; i < 4; ++i) {
        float4 o = make_float4(acc[i][0], acc[i][1], acc[i][2], acc[i][3]);
        *(float4*)&C[(size_t)(row0 + ty * 4 + i) * Nc + col0 + tx * 4] = o;
    }
}

// ---------------- self-loop init: B[i][f] = A[i][f] * dis[i]^2 ----------------
__global__ __launch_bounds__(256) void init_self_kernel(const float* __restrict__ A,
                                                        const float* __restrict__ dis,
                                                        float* __restrict__ B, int total4) {
    int t = blockIdx.x * blockDim.x + threadIdx.x;
    if (t >= total4) return;
    int i = t >> 6;  // HD/4 = 64 float4 per row
    float s = dis[i] * dis[i];
    float4 v = *(const float4*)&A[(size_t)t * 4];
    v.x *= s; v.y *= s; v.z *= s; v.w *= s;
    *(float4*)&B[(size_t)t * 4] = v;
}

// ---------------- edge scatter: B[col] += A[row] * dis[row]*dis[col] ----------------
// one wave (64 lanes) per edge, 4 floats per lane (HD=256 wide)
__global__ __launch_bounds__(256) void scatter_kernel(const int* __restrict__ ei,
                                                      const float* __restrict__ dis,
                                                      const float* __restrict__ A,
                                                      float* __restrict__ B, int E) {
    int wave = (blockIdx.x * blockDim.x + threadIdx.x) >> 6;
    int lane = threadIdx.x & 63;
    if (wave >= E) return;
    int r = ei[wave], c = ei[E + wave];
    float nrm = dis[r] * dis[c];
    const float* a = A + (size_t)r * HD;
    float* b = B + (size_t)c * HD;
    float4 v = *(const float4*)&a[lane * 4];
    atomicAdd(&b[lane * 4 + 0], v.x * nrm);
    atomicAdd(&b[lane * 4 + 1], v.y * nrm);
    atomicAdd(&b[lane * 4 + 2], v.z * nrm);
    atomicAdd(&b[lane * 4 + 3], v.w * nrm);
}

// ---------------- relu(x + bias) in place, width HD ----------------
__global__ __launch_bounds__(256) void relu_bias_kernel(float* __restrict__ B,
                                                        const float* __restrict__ bias,
                                                        int total4) {
    int t = blockIdx.x * blockDim.x + threadIdx.x;
    if (t >= total4) return;
    int f4 = (t & 63) << 2;  // HD/4 = 64
    float4 v = *(float4*)&B[(size_t)t * 4];
    v.x = fmaxf(v.x + bias[f4 + 0], 0.f);
    v.y = fmaxf(v.y + bias[f4 + 1], 0.f);
    v.z = fmaxf(v.z + bias[f4 + 2], 0.f);
    v.w = fmaxf(v.w + bias[f4 + 3], 0.f);
    *(float4*)&B[(size_t)t * 4] = v;
}

// ---------------- split acc[N,256] -> mu, logvar (+bias), and z copy ----------------
__global__ __launch_bounds__(256) void writeout_kernel(const float* __restrict__ acc,
                                                       const float* __restrict__ bmu,
                                                       const float* __restrict__ blv,
                                                       float* __restrict__ out_mu,
                                                       float* __restrict__ out_lv,
                                                       float* __restrict__ z) {
    int t = blockIdx.x * blockDim.x + threadIdx.x;  // NN*HD2
    int i = t >> 7, j = t & 127;
    float mu = acc[(size_t)i * HD + j] + bmu[j];
    float lv = acc[(size_t)i * HD + HD2 + j] + blv[j];
    out_mu[t] = mu;
    out_lv[t] = lv;
    z[t] = mu;
}

// ---------------- 32x32 LDS transpose: out[c][r] = in[r][c] ----------------
__global__ __launch_bounds__(256) void transpose_kernel(const float* __restrict__ in,
                                                        float* __restrict__ out,
                                                        int R, int C) {
    __shared__ float t[32][33];
    int c0 = blockIdx.x * 32, r0 = blockIdx.y * 32;
    int lx = threadIdx.x, ly = threadIdx.y;  // 32 x 8
    for (int yy = ly; yy < 32; yy += 8)
        t[yy][lx] = in[(size_t)(r0 + yy) * C + c0 + lx];
    __syncthreads();
    for (int yy = ly; yy < 32; yy += 8)
        out[(size_t)(c0 + yy) * R + r0 + lx] = t[lx][yy];
}

extern "C" void kernel_launch(void* const* d_in, const int* in_sizes, int n_in,
                              void* d_out, int out_size, void* d_ws, size_t ws_size,
                              hipStream_t stream) {
    const float* x     = (const float*)d_in[0];
    const int*   ei    = (const int*)d_in[1];
    const float* W_enc = (const float*)d_in[2];
    const float* b_enc = (const float*)d_in[3];
    const float* W1    = (const float*)d_in[4];
    const float* b1    = (const float*)d_in[5];
    const float* W2    = (const float*)d_in[6];
    const float* b2    = (const float*)d_in[7];

    float* out    = (float*)d_out;
    float* adj    = out;
    float* out_mu = out + (size_t)NN * NN;
    float* out_lv = out_mu + (size_t)NN * HD2;

    float* ws   = (float*)d_ws;
    float* dis  = ws;                           // NN
    float* bufA = ws + NN;                      // NN*HD
    float* bufB = bufA + (size_t)NN * HD;       // NN*HD
    float* Wcat = bufB + (size_t)NN * HD;       // HD*HD
    float* Zt   = Wcat + HD * HD;               // HD2*NN

    // 1. degree -> dis = rsqrt(deg+1)
    hipMemsetAsync(dis, 0, NN * sizeof(float), stream);
    count_deg_kernel<<<NE / 256, 256, 0, stream>>>(ei + NE, dis, NE);
    finish_dis_kernel<<<NN / 256, 256, 0, stream>>>(dis, NN);

    // 2. Wcat = [W1 | W2]
    build_wcat_kernel<<<HD * HD / 256, 256, 0, stream>>>(W1, W2, Wcat);

    // 3. XW = x @ W_enc
    gemm_f32_kernel<<<dim3(HD / 64, NN / 64), 256, 0, stream>>>(x, W_enc, bufA, NN, HD, FIN);

    // 4. aggregate layer 1: bufB = scatter(bufA) ; relu(+b_enc)
    init_self_kernel<<<NN * HD / 4 / 256, 256, 0, stream>>>(bufA, dis, bufB, NN * HD / 4);
    scatter_kernel<<<NE / 4, 256, 0, stream>>>(ei, dis, bufA, bufB, NE);
    relu_bias_kernel<<<NN * HD / 4 / 256, 256, 0, stream>>>(bufB, b_enc, NN * HD / 4);

    // 5. HW = h @ [W1|W2]
    gemm_f32_kernel<<<dim3(HD / 64, NN / 64), 256, 0, stream>>>(bufB, Wcat, bufA, NN, HD, HD);

    // 6. aggregate layer 2
    init_self_kernel<<<NN * HD / 4 / 256, 256, 0, stream>>>(bufA, dis, bufB, NN * HD / 4);
    scatter_kernel<<<NE / 4, 256, 0, stream>>>(ei, dis, bufA, bufB, NE);

    // 7. mu/logvar out (+biases), z (row-major) into bufA
    writeout_kernel<<<NN * HD2 / 256, 256, 0, stream>>>(bufB, b1, b2, out_mu, out_lv, bufA);

    // 8. Zt = z^T
    transpose_kernel<<<dim3(HD2 / 32, NN / 32), dim3(32, 8), 0, stream>>>(bufA, Zt, NN, HD2);

    // 9. Adj = z @ z^T
    gemm_f32_kernel<<<dim3(NN / 64, NN / 64), 256, 0, stream>>>(bufA, Zt, adj, NN, NN, HD2);
}

// Round 2
// 1264.792 us; speedup vs baseline: 3.6554x; 3.6554x over previous
//
#include <hip/hip_runtime.h>
#include <hip/hip_bf16.h>

#define NN 16384
#define NE 524288
#define FIN 512
#define HD 256
#define HD2 128

// ---------------- degree count (int) ----------------
__global__ __launch_bounds__(256) void count_deg_kernel(const int* __restrict__ col,
                                                        int* __restrict__ cnt, int E) {
    int e = blockIdx.x * blockDim.x + threadIdx.x;
    if (e < E) atomicAdd(&cnt[col[e]], 1);
}

__global__ __launch_bounds__(256) void finish_dis_kernel(const int* __restrict__ cnt,
                                                         float* __restrict__ dis, int n) {
    int i = blockIdx.x * blockDim.x + threadIdx.x;
    if (i < n) dis[i] = rsqrtf((float)cnt[i] + 1.0f);  // +1 self-loop
}

// ---------------- exclusive prefix scan of 16384 counts (single block) ----------------
__global__ __launch_bounds__(256) void scan_kernel(const int* __restrict__ cnt,
                                                   int* __restrict__ off) {
    __shared__ int part[256];
    const int t = threadIdx.x;
    const int base = t * 64;
    int s = 0;
#pragma unroll 4
    for (int j = 0; j < 64; ++j) s += cnt[base + j];
    part[t] = s;
    __syncthreads();
    for (int d = 1; d < 256; d <<= 1) {
        int v = (t >= d) ? part[t - d] : 0;
        __syncthreads();
        part[t] += v;
        __syncthreads();
    }
    int run = (t == 0) ? 0 : part[t - 1];
    for (int j = 0; j < 64; ++j) {
        off[base + j] = run;
        run += cnt[base + j];
    }
    if (t == 255) off[NN] = run;
}

// ---------------- CSR fill: srcs + per-edge weight dis[src] ----------------
__global__ __launch_bounds__(256) void fill_kernel(const int* __restrict__ ei,
                                                   const int* __restrict__ off,
                                                   int* __restrict__ cur,
                                                   const float* __restrict__ dis,
                                                   int* __restrict__ srcs,
                                                   float* __restrict__ wgt, int E) {
    int e = blockIdx.x * blockDim.x + threadIdx.x;
    if (e >= E) return;
    int r = ei[e], c = ei[E + e];
    int pos = off[c] + atomicAdd(&cur[c], 1);
    srcs[pos] = r;
    wgt[pos] = dis[r];
}

// ---------------- build concatenated [W1 | W2] ----------------
__global__ __launch_bounds__(256) void build_wcat_kernel(const float* __restrict__ W1,
                                                         const float* __restrict__ W2,
                                                         float* __restrict__ Wcat) {
    int t = blockIdx.x * blockDim.x + threadIdx.x;  // HD*HD
    int k = t / HD, j = t % HD;
    Wcat[t] = (j < HD2) ? W1[k * HD2 + j] : W2[k * HD2 + (j - HD2)];
}

// ---------------- generic fp32 tiled GEMM: C[M,Nc] = A[M,K] @ B[K,Nc] ----------------
__global__ __launch_bounds__(256) void gemm_f32_kernel(const float* __restrict__ A,
                                                       const float* __restrict__ B,
                                                       float* __restrict__ C,
                                                       int M, int Nc, int K) {
    __shared__ float As[16][68];  // transposed A tile: As[k][m]
    __shared__ float Bs[16][68];  // Bs[k][n]
    const int tid = threadIdx.x;
    const int tx = tid & 15, ty = tid >> 4;
    const int row0 = blockIdx.y * 64, col0 = blockIdx.x * 64;
    const int am = tid >> 2, ak4 = (tid & 3) << 2;
    const int bk = tid >> 4, bn4 = (tid & 15) << 2;
    float acc[4][4] = {};
    for (int k0 = 0; k0 < K; k0 += 16) {
        float4 va = *(const float4*)&A[(size_t)(row0 + am) * K + k0 + ak4];
        As[ak4 + 0][am] = va.x;
        As[ak4 + 1][am] = va.y;
        As[ak4 + 2][am] = va.z;
        As[ak4 + 3][am] = va.w;
        *(float4*)&Bs[bk][bn4] = *(const float4*)&B[(size_t)(k0 + bk) * Nc + col0 + bn4];
        __syncthreads();
#pragma unroll
        for (int k = 0; k < 16; ++k) {
            const float4 av = *(const float4*)&As[k][ty << 2];
            const float4 bv = *(const float4*)&Bs[k][tx << 2];
            const float a0 = av.x, a1 = av.y, a2 = av.z, a3 = av.w;
            const float c0 = bv.x, c1 = bv.y, c2 = bv.z, c3 = bv.w;
            acc[0][0] += a0 * c0; acc[0][1] += a0 * c1; acc[0][2] += a0 * c2; acc[0][3] += a0 * c3;
            acc[1][0] += a1 * c0; acc[1][1] += a1 * c1; acc[1][2] += a1 * c2; acc[1][3] += a1 * c3;
            acc[2][0] += a2 * c0; acc[2][1] += a2 * c1; acc[2][2] += a2 * c2; acc[2][3] += a2 * c3;
            acc[3][0] += a3 * c0; acc[3][1] += a3 * c1; acc[3][2] += a3 * c2; acc[3][3] += a3 * c3;
        }
        __syncthreads();
    }
#pragma unroll
    for (int i = 0; i < 4; ++i) {
        float4 o = make_float4(acc[i][0], acc[i][1], acc[i][2], acc[i][3]);
        *(float4*)&C[(size_t)(row0 + ty * 4 + i) * Nc + col0 + tx * 4] = o;
    }
}

// ---------------- gather aggregation: one wave per destination node ----------------
// out_i = dis[i] * ( dis[i]*A[i] + sum_{e: col=i} dis[src_e]*A[src_e] )
// mode 0: B[i] = relu(out_i + bias)            (encoder layer)
// mode 1: mu/logvar split (+b1/b2), z copy     (second layer)
__global__ __launch_bounds__(256) void gather_kernel(const int* __restrict__ off,
                                                     const int* __restrict__ srcs,
                                                     const float* __restrict__ wgt,
                                                     const float* __restrict__ dis,
                                                     const float* __restrict__ A,
                                                     const float* __restrict__ bias,
                                                     float* __restrict__ B,
                                                     const float* __restrict__ b1,
                                                     const float* __restrict__ b2,
                                                     float* __restrict__ out_mu,
                                                     float* __restrict__ out_lv,
                                                     int mode) {
    const int wave = (blockIdx.x * blockDim.x + threadIdx.x) >> 6;
    const int lane = threadIdx.x & 63;
    if (wave >= NN) return;
    const int i = wave;
    const float di = dis[i];
    const int j = lane * 4;
    float4 acc = *(const float4*)&A[(size_t)i * HD + j];
    acc.x *= di; acc.y *= di; acc.z *= di; acc.w *= di;
    const int k1 = off[i + 1];
    for (int k = off[i]; k < k1; ++k) {
        const int s = srcs[k];
        const float w = wgt[k];
        const float4 v = *(const float4*)&A[(size_t)s * HD + j];
        acc.x += w * v.x;
        acc.y += w * v.y;
        acc.z += w * v.z;
        acc.w += w * v.w;
    }
    acc.x *= di; acc.y *= di; acc.z *= di; acc.w *= di;
    if (mode == 0) {
        const float4 bb = *(const float4*)&bias[j];
        acc.x = fmaxf(acc.x + bb.x, 0.f);
        acc.y = fmaxf(acc.y + bb.y, 0.f);
        acc.z = fmaxf(acc.z + bb.z, 0.f);
        acc.w = fmaxf(acc.w + bb.w, 0.f);
        *(float4*)&B[(size_t)i * HD + j] = acc;
    } else {
        if (j < HD2) {
            const float4 bb = *(const float4*)&b1[j];
            acc.x += bb.x; acc.y += bb.y; acc.z += bb.z; acc.w += bb.w;
            *(float4*)&out_mu[(size_t)i * HD2 + j] = acc;
            *(float4*)&B[(size_t)i * HD2 + j] = acc;  // z
        } else {
            const int jj = j - HD2;
            const float4 bb = *(const float4*)&b2[jj];
            acc.x += bb.x; acc.y += bb.y; acc.z += bb.z; acc.w += bb.w;
            *(float4*)&out_lv[(size_t)i * HD2 + jj] = acc;
        }
    }
}

// ---------------- 32x32 LDS transpose: out[c][r] = in[r][c] ----------------
__global__ __launch_bounds__(256) void transpose_kernel(const float* __restrict__ in,
                                                        float* __restrict__ out,
                                                        int R, int C) {
    __shared__ float t[32][33];
    int c0 = blockIdx.x * 32, r0 = blockIdx.y * 32;
    int lx = threadIdx.x, ly = threadIdx.y;  // 32 x 8
    for (int yy = ly; yy < 32; yy += 8)
        t[yy][lx] = in[(size_t)(r0 + yy) * C + c0 + lx];
    __syncthreads();
    for (int yy = ly; yy < 32; yy += 8)
        out[(size_t)(c0 + yy) * R + r0 + lx] = t[lx][yy];
}

extern "C" void kernel_launch(void* const* d_in, const int* in_sizes, int n_in,
                              void* d_out, int out_size, void* d_ws, size_t ws_size,
                              hipStream_t stream) {
    const float* x     = (const float*)d_in[0];
    const int*   ei    = (const int*)d_in[1];
    const float* W_enc = (const float*)d_in[2];
    const float* b_enc = (const float*)d_in[3];
    const float* W1    = (const float*)d_in[4];
    const float* b1    = (const float*)d_in[5];
    const float* W2    = (const float*)d_in[6];
    const float* b2    = (const float*)d_in[7];

    float* out    = (float*)d_out;
    float* adj    = out;
    float* out_mu = out + (size_t)NN * NN;
    float* out_lv = out_mu + (size_t)NN * HD2;

    float* ws   = (float*)d_ws;
    float* dis  = ws;                           // NN floats
    float* bufA = ws + NN;                      // NN*HD
    float* bufB = bufA + (size_t)NN * HD;       // NN*HD
    float* Wcat = bufB + (size_t)NN * HD;       // HD*HD
    float* Zt   = Wcat + HD * HD;               // HD2*NN
    float* wgt  = Zt + (size_t)HD2 * NN;        // NE floats
    int*   icnt = (int*)(wgt + NE);             // NN ints
    int*   off  = icnt + NN;                    // NN+1 ints
    int*   cur  = off + NN + 1;                 // NN ints
    int*   srcs = cur + NN;                     // NE ints

    // 1. CSR build: count -> dis, scan -> offsets, fill (srcs + weights)
    hipMemsetAsync(icnt, 0, NN * sizeof(int), stream);
    hipMemsetAsync(cur, 0, NN * sizeof(int), stream);
    count_deg_kernel<<<NE / 256, 256, 0, stream>>>(ei + NE, icnt, NE);
    finish_dis_kernel<<<NN / 256, 256, 0, stream>>>(icnt, dis, NN);
    scan_kernel<<<1, 256, 0, stream>>>(icnt, off);
    fill_kernel<<<NE / 256, 256, 0, stream>>>(ei, off, cur, dis, srcs, wgt, NE);

    // 2. Wcat = [W1 | W2]
    build_wcat_kernel<<<HD * HD / 256, 256, 0, stream>>>(W1, W2, Wcat);

    // 3. XW = x @ W_enc
    gemm_f32_kernel<<<dim3(HD / 64, NN / 64), 256, 0, stream>>>(x, W_enc, bufA, NN, HD, FIN);

    // 4. aggregate layer 1 (gather) + relu + bias -> bufB
    gather_kernel<<<NN * 64 / 256, 256, 0, stream>>>(off, srcs, wgt, dis, bufA, b_enc,
                                                     bufB, nullptr, nullptr, nullptr, nullptr, 0);

    // 5. HW = h @ [W1|W2]
    gemm_f32_kernel<<<dim3(HD / 64, NN / 64), 256, 0, stream>>>(bufB, Wcat, bufA, NN, HD, HD);

    // 6. aggregate layer 2 (gather) + mu/logvar writeout; z -> bufB
    gather_kernel<<<NN * 64 / 256, 256, 0, stream>>>(off, srcs, wgt, dis, bufA, nullptr,
                                                     bufB, b1, b2, out_mu, out_lv, 1);

    // 7. Zt = z^T
    transpose_kernel<<<dim3(HD2 / 32, NN / 32), dim3(32, 8), 0, stream>>>(bufB, Zt, NN, HD2);

    // 8. Adj = z @ z^T
    gemm_f32_kernel<<<dim3(NN / 64, NN / 64), 256, 0, stream>>>(bufB, Zt, adj, NN, NN, HD2);
}

// Round 3
// 661.514 us; speedup vs baseline: 6.9890x; 1.9120x over previous
//
#include <hip/hip_runtime.h>
#include <hip/hip_bf16.h>

#define NN 16384
#define NE 524288
#define FIN 512
#define HD 256
#define HD2 128

typedef __attribute__((ext_vector_type(8))) short bfrag;   // 8 bf16 = 4 VGPRs
typedef __attribute__((ext_vector_type(4))) float ffrag;   // 4 f32 acc

static __device__ __forceinline__ ushort f2bf(float f) {
    uint u = __float_as_uint(f);
    uint r = (u + 0x7fff + ((u >> 16) & 1)) >> 16;  // round-nearest-even
    return (ushort)r;
}
static __device__ __forceinline__ float bf2f(ushort h) {
    return __uint_as_float(((uint)h) << 16);
}

// ---------------- degree count (int) ----------------
__global__ __launch_bounds__(256) void count_deg_kernel(const int* __restrict__ col,
                                                        int* __restrict__ cnt, int E) {
    int e = blockIdx.x * blockDim.x + threadIdx.x;
    if (e < E) atomicAdd(&cnt[col[e]], 1);
}

__global__ __launch_bounds__(256) void finish_dis_kernel(const int* __restrict__ cnt,
                                                         float* __restrict__ dis, int n) {
    int i = blockIdx.x * blockDim.x + threadIdx.x;
    if (i < n) dis[i] = rsqrtf((float)cnt[i] + 1.0f);  // +1 self-loop
}

// ---------------- exclusive prefix scan of 16384 counts (single block) ----------------
__global__ __launch_bounds__(256) void scan_kernel(const int* __restrict__ cnt,
                                                   int* __restrict__ off) {
    __shared__ int part[256];
    const int t = threadIdx.x;
    const int base = t * 64;
    int s = 0;
#pragma unroll 4
    for (int j = 0; j < 64; ++j) s += cnt[base + j];
    part[t] = s;
    __syncthreads();
    for (int d = 1; d < 256; d <<= 1) {
        int v = (t >= d) ? part[t - d] : 0;
        __syncthreads();
        part[t] += v;
        __syncthreads();
    }
    int run = (t == 0) ? 0 : part[t - 1];
    for (int j = 0; j < 64; ++j) {
        off[base + j] = run;
        run += cnt[base + j];
    }
    if (t == 255) off[NN] = run;
}

// ---------------- CSR fill: srcs + per-edge weight dis[src] ----------------
__global__ __launch_bounds__(256) void fill_kernel(const int* __restrict__ ei,
                                                   const int* __restrict__ off,
                                                   int* __restrict__ cur,
                                                   const float* __restrict__ dis,
                                                   int* __restrict__ srcs,
                                                   float* __restrict__ wgt, int E) {
    int e = blockIdx.x * blockDim.x + threadIdx.x;
    if (e >= E) return;
    int r = ei[e], c = ei[E + e];
    int pos = off[c] + atomicAdd(&cur[c], 1);
    srcs[pos] = r;
    wgt[pos] = dis[r];
}

// ---------------- build concatenated [W1 | W2] ----------------
__global__ __launch_bounds__(256) void build_wcat_kernel(const float* __restrict__ W1,
                                                         const float* __restrict__ W2,
                                                         float* __restrict__ Wcat) {
    int t = blockIdx.x * blockDim.x + threadIdx.x;  // HD*HD
    int k = t / HD, j = t % HD;
    Wcat[t] = (j < HD2) ? W1[k * HD2 + j] : W2[k * HD2 + (j - HD2)];
}

// ---------------- generic fp32 tiled GEMM: C[M,Nc] = A[M,K] @ B[K,Nc] ----------------
__global__ __launch_bounds__(256) void gemm_f32_kernel(const float* __restrict__ A,
                                                       const float* __restrict__ B,
                                                       float* __restrict__ C,
                                                       int M, int Nc, int K) {
    __shared__ float As[16][68];  // transposed A tile: As[k][m]
    __shared__ float Bs[16][68];  // Bs[k][n]
    const int tid = threadIdx.x;
    const int tx = tid & 15, ty = tid >> 4;
    const int row0 = blockIdx.y * 64, col0 = blockIdx.x * 64;
    const int am = tid >> 2, ak4 = (tid & 3) << 2;
    const int bk = tid >> 4, bn4 = (tid & 15) << 2;
    float acc[4][4] = {};
    for (int k0 = 0; k0 < K; k0 += 16) {
        float4 va = *(const float4*)&A[(size_t)(row0 + am) * K + k0 + ak4];
        As[ak4 + 0][am] = va.x;
        As[ak4 + 1][am] = va.y;
        As[ak4 + 2][am] = va.z;
        As[ak4 + 3][am] = va.w;
        *(float4*)&Bs[bk][bn4] = *(const float4*)&B[(size_t)(k0 + bk) * Nc + col0 + bn4];
        __syncthreads();
#pragma unroll
        for (int k = 0; k < 16; ++k) {
            const float4 av = *(const float4*)&As[k][ty << 2];
            const float4 bv = *(const float4*)&Bs[k][tx << 2];
            const float a0 = av.x, a1 = av.y, a2 = av.z, a3 = av.w;
            const float c0 = bv.x, c1 = bv.y, c2 = bv.z, c3 = bv.w;
            acc[0][0] += a0 * c0; acc[0][1] += a0 * c1; acc[0][2] += a0 * c2; acc[0][3] += a0 * c3;
            acc[1][0] += a1 * c0; acc[1][1] += a1 * c1; acc[1][2] += a1 * c2; acc[1][3] += a1 * c3;
            acc[2][0] += a2 * c0; acc[2][1] += a2 * c1; acc[2][2] += a2 * c2; acc[2][3] += a2 * c3;
            acc[3][0] += a3 * c0; acc[3][1] += a3 * c1; acc[3][2] += a3 * c2; acc[3][3] += a3 * c3;
        }
        __syncthreads();
    }
#pragma unroll
    for (int i = 0; i < 4; ++i) {
        float4 o = make_float4(acc[i][0], acc[i][1], acc[i][2], acc[i][3]);
        *(float4*)&C[(size_t)(row0 + ty * 4 + i) * Nc + col0 + tx * 4] = o;
    }
}

// ---------------- gather aggregation: one wave per destination node ----------------
// out_i = dis[i] * ( dis[i]*A[i] + sum_{e: col=i} dis[src_e]*A[src_e] )
// mode 0: B[i] = relu(out_i + bias)
// mode 1: mu/logvar split (+b1/b2); z emitted as swizzled bf16 hi|lo ext row
__global__ __launch_bounds__(256) void gather_kernel(const int* __restrict__ off,
                                                     const int* __restrict__ srcs,
                                                     const float* __restrict__ wgt,
                                                     const float* __restrict__ dis,
                                                     const float* __restrict__ A,
                                                     const float* __restrict__ bias,
                                                     float* __restrict__ B,
                                                     const float* __restrict__ b1,
                                                     const float* __restrict__ b2,
                                                     float* __restrict__ out_mu,
                                                     float* __restrict__ out_lv,
                                                     ushort* __restrict__ zext,
                                                     int mode) {
    const int wave = (blockIdx.x * blockDim.x + threadIdx.x) >> 6;
    const int lane = threadIdx.x & 63;
    if (wave >= NN) return;
    const int i = wave;
    const float di = dis[i];
    const int j = lane * 4;
    float4 acc = *(const float4*)&A[(size_t)i * HD + j];
    acc.x *= di; acc.y *= di; acc.z *= di; acc.w *= di;
    const int k1 = off[i + 1];
    for (int k = off[i]; k < k1; ++k) {
        const int s = srcs[k];
        const float w = wgt[k];
        const float4 v = *(const float4*)&A[(size_t)s * HD + j];
        acc.x += w * v.x;
        acc.y += w * v.y;
        acc.z += w * v.z;
        acc.w += w * v.w;
    }
    acc.x *= di; acc.y *= di; acc.z *= di; acc.w *= di;
    if (mode == 0) {
        const float4 bb = *(const float4*)&bias[j];
        acc.x = fmaxf(acc.x + bb.x, 0.f);
        acc.y = fmaxf(acc.y + bb.y, 0.f);
        acc.z = fmaxf(acc.z + bb.z, 0.f);
        acc.w = fmaxf(acc.w + bb.w, 0.f);
        *(float4*)&B[(size_t)i * HD + j] = acc;
    } else {
        if (j < HD2) {
            const float4 bb = *(const float4*)&b1[j];
            acc.x += bb.x; acc.y += bb.y; acc.z += bb.z; acc.w += bb.w;
            *(float4*)&out_mu[(size_t)i * HD2 + j] = acc;
            // emit z as bf16 hi/lo into swizzled ext row: chunk' = chunk ^ (i&7)
            ushort h0 = f2bf(acc.x), h1 = f2bf(acc.y), h2 = f2bf(acc.z), h3 = f2bf(acc.w);
            ushort l0 = f2bf(acc.x - bf2f(h0));
            ushort l1 = f2bf(acc.y - bf2f(h1));
            ushort l2 = f2bf(acc.z - bf2f(h2));
            ushort l3 = f2bf(acc.w - bf2f(h3));
            const int c = lane >> 1;                 // logical hi chunk (8 feats)
            const int half = (lane & 1) * 4;
            const int sc  = (c        ) ^ (i & 7);   // XOR affects low 3 bits only
            const int scl = (16 + c   ) ^ (i & 7);
            ushort* zr = zext + (size_t)i * 256;
            ushort4 hv; hv.x = h0; hv.y = h1; hv.z = h2; hv.w = h3;
            ushort4 lv; lv.x = l0; lv.y = l1; lv.z = l2; lv.w = l3;
            *(ushort4*)&zr[sc * 8 + half]  = hv;
            *(ushort4*)&zr[scl * 8 + half] = lv;
        } else {
            const int jj = j - HD2;
            const float4 bb = *(const float4*)&b2[jj];
            acc.x += bb.x; acc.y += bb.y; acc.z += bb.z; acc.w += bb.w;
            *(float4*)&out_lv[(size_t)i * HD2 + jj] = acc;
        }
    }
}

// ---------------- Adj = z z^T via bf16 hi/lo split MFMA ----------------
// zext: [NN][256] bf16 (hi|lo), chunk-swizzled (chunk ^= row&7).
// Block: 128x128 tile, 256 thr = 4 waves in 2x2 of 64x64; full K staged in LDS.
__global__ __launch_bounds__(256) void zz_mfma_kernel(const ushort* __restrict__ zext,
                                                      float* __restrict__ adj) {
    extern __shared__ ushort lds[];          // 128 KiB: A[128][256] + B[128][256]
    ushort* Ash = lds;
    ushort* Bsh = lds + 128 * 256;
    const int tid = threadIdx.x;
    const int lane = tid & 63;
    const int wid = tid >> 6;
    const int bm = blockIdx.y, bn = blockIdx.x;

    // ---- stage: verbatim linear copy of 128 swizzled 512B rows per operand ----
    {
        const uint4* gA = (const uint4*)(zext + (size_t)bm * 128 * 256);
        const uint4* gB = (const uint4*)(zext + (size_t)bn * 128 * 256);
        uint4* lA = (uint4*)Ash;
        uint4* lB = (uint4*)Bsh;
#pragma unroll
        for (int it = 0; it < 16; ++it) lA[it * 256 + tid] = gA[it * 256 + tid];
#pragma unroll
        for (int it = 0; it < 16; ++it) lB[it * 256 + tid] = gB[it * 256 + tid];
    }
    __syncthreads();

    const int wm = (wid >> 1) * 64, wn = (wid & 1) * 64;
    const int fr = lane & 15;   // row/col within 16x16 frag
    const int g  = lane >> 4;   // k-group (8 elems each)

    ffrag acc[4][4];
#pragma unroll
    for (int mf = 0; mf < 4; ++mf)
#pragma unroll
        for (int nf = 0; nf < 4; ++nf) acc[mf][nf] = (ffrag){0.f, 0.f, 0.f, 0.f};

#pragma unroll
    for (int kk = 0; kk < 4; ++kk) {
        bfrag ahi[4], alo[4], bhi[4], blo[4];
#pragma unroll
        for (int mf = 0; mf < 4; ++mf) {
            const int r = wm + mf * 16 + fr;
            const int swz = r & 7;
            ahi[mf] = *(const bfrag*)&Ash[r * 256 + (((kk * 4 + g)      ) ^ swz) * 8];
            alo[mf] = *(const bfrag*)&Ash[r * 256 + (((kk * 4 + g) + 16 ) ^ swz) * 8];
        }
#pragma unroll
        for (int nf = 0; nf < 4; ++nf) {
            const int r = wn + nf * 16 + fr;
            const int swz = r & 7;
            bhi[nf] = *(const bfrag*)&Bsh[r * 256 + (((kk * 4 + g)      ) ^ swz) * 8];
            blo[nf] = *(const bfrag*)&Bsh[r * 256 + (((kk * 4 + g) + 16 ) ^ swz) * 8];
        }
#pragma unroll
        for (int mf = 0; mf < 4; ++mf)
#pragma unroll
            for (int nf = 0; nf < 4; ++nf) {
                acc[mf][nf] = __builtin_amdgcn_mfma_f32_16x16x32_bf16(ahi[mf], bhi[nf], acc[mf][nf], 0, 0, 0);
                acc[mf][nf] = __builtin_amdgcn_mfma_f32_16x16x32_bf16(ahi[mf], blo[nf], acc[mf][nf], 0, 0, 0);
                acc[mf][nf] = __builtin_amdgcn_mfma_f32_16x16x32_bf16(alo[mf], bhi[nf], acc[mf][nf], 0, 0, 0);
                acc[mf][nf] = __builtin_amdgcn_mfma_f32_16x16x32_bf16(alo[mf], blo[nf], acc[mf][nf], 0, 0, 0);
            }
    }

    // ---- store: C/D layout col=lane&15, row=(lane>>4)*4+reg ----
    const size_t row0 = (size_t)bm * 128 + wm;
    const int col0 = bn * 128 + wn;
#pragma unroll
    for (int mf = 0; mf < 4; ++mf) {
#pragma unroll
        for (int reg = 0; reg < 4; ++reg) {
            const size_t r = row0 + mf * 16 + g * 4 + reg;
            float* outp = adj + r * NN + col0 + fr;
#pragma unroll
            for (int nf = 0; nf < 4; ++nf) outp[nf * 16] = acc[mf][nf][reg];
        }
    }
}

extern "C" void kernel_launch(void* const* d_in, const int* in_sizes, int n_in,
                              void* d_out, int out_size, void* d_ws, size_t ws_size,
                              hipStream_t stream) {
    const float* x     = (const float*)d_in[0];
    const int*   ei    = (const int*)d_in[1];
    const float* W_enc = (const float*)d_in[2];
    const float* b_enc = (const float*)d_in[3];
    const float* W1    = (const float*)d_in[4];
    const float* b1    = (const float*)d_in[5];
    const float* W2    = (const float*)d_in[6];
    const float* b2    = (const float*)d_in[7];

    float* out    = (float*)d_out;
    float* adj    = out;
    float* out_mu = out + (size_t)NN * NN;
    float* out_lv = out_mu + (size_t)NN * HD2;

    float*  ws   = (float*)d_ws;
    float*  dis  = ws;                           // NN floats
    float*  bufA = ws + NN;                      // NN*HD
    float*  bufB = bufA + (size_t)NN * HD;       // NN*HD
    float*  Wcat = bufB + (size_t)NN * HD;       // HD*HD
    ushort* zext = (ushort*)(Wcat + HD * HD);    // NN*256 ushort (8 MB)
    float*  wgt  = (float*)(zext + (size_t)NN * 256);  // NE floats
    int*    icnt = (int*)(wgt + NE);             // NN ints
    int*    off  = icnt + NN;                    // NN+1 ints
    int*    cur  = off + NN + 1;                 // NN ints
    int*    srcs = cur + NN;                     // NE ints

    // 1. CSR build: count -> dis, scan -> offsets, fill (srcs + weights)
    hipMemsetAsync(icnt, 0, NN * sizeof(int), stream);
    hipMemsetAsync(cur, 0, NN * sizeof(int), stream);
    count_deg_kernel<<<NE / 256, 256, 0, stream>>>(ei + NE, icnt, NE);
    finish_dis_kernel<<<NN / 256, 256, 0, stream>>>(icnt, dis, NN);
    scan_kernel<<<1, 256, 0, stream>>>(icnt, off);
    fill_kernel<<<NE / 256, 256, 0, stream>>>(ei, off, cur, dis, srcs, wgt, NE);

    // 2. Wcat = [W1 | W2]
    build_wcat_kernel<<<HD * HD / 256, 256, 0, stream>>>(W1, W2, Wcat);

    // 3. XW = x @ W_enc
    gemm_f32_kernel<<<dim3(HD / 64, NN / 64), 256, 0, stream>>>(x, W_enc, bufA, NN, HD, FIN);

    // 4. aggregate layer 1 (gather) + relu + bias -> bufB
    gather_kernel<<<NN * 64 / 256, 256, 0, stream>>>(off, srcs, wgt, dis, bufA, b_enc,
                                                     bufB, nullptr, nullptr, nullptr, nullptr,
                                                     nullptr, 0);

    // 5. HW = h @ [W1|W2]
    gemm_f32_kernel<<<dim3(HD / 64, NN / 64), 256, 0, stream>>>(bufB, Wcat, bufA, NN, HD, HD);

    // 6. aggregate layer 2 (gather): mu/logvar out + z as swizzled bf16 hi/lo
    gather_kernel<<<NN * 64 / 256, 256, 0, stream>>>(off, srcs, wgt, dis, bufA, nullptr,
                                                     nullptr, b1, b2, out_mu, out_lv,
                                                     zext, 1);

    // 7. Adj = z z^T (bf16 hi/lo split, 4-product MFMA)
    zz_mfma_kernel<<<dim3(NN / 128, NN / 128), 256, 131072, stream>>>(zext, adj);
}

// Round 4
// 517.982 us; speedup vs baseline: 8.9256x; 1.2771x over previous
//
#include <hip/hip_runtime.h>
#include <hip/hip_bf16.h>

#define NN 16384
#define NE 524288
#define FIN 512
#define HD 256
#define HD2 128

typedef __attribute__((ext_vector_type(8))) short bfrag;   // 8 bf16 = 4 VGPRs
typedef __attribute__((ext_vector_type(4))) float ffrag;   // 4 f32 acc

union U8 { ushort u[8]; uint4 v; };

static __device__ __forceinline__ ushort f2bf(float f) {
    uint u = __float_as_uint(f);
    return (ushort)((u + 0x7fff + ((u >> 16) & 1)) >> 16);  // RNE
}
static __device__ __forceinline__ float bf2f(ushort h) {
    return __uint_as_float(((uint)h) << 16);
}

// ---------------- CSR build ----------------
__global__ __launch_bounds__(256) void count_deg_kernel(const int* __restrict__ col,
                                                        int* __restrict__ cnt, int E) {
    int e = blockIdx.x * blockDim.x + threadIdx.x;
    if (e < E) atomicAdd(&cnt[col[e]], 1);
}

__global__ __launch_bounds__(256) void finish_dis_kernel(const int* __restrict__ cnt,
                                                         float* __restrict__ dis, int n) {
    int i = blockIdx.x * blockDim.x + threadIdx.x;
    if (i < n) dis[i] = rsqrtf((float)cnt[i] + 1.0f);
}

__global__ __launch_bounds__(256) void scan_kernel(const int* __restrict__ cnt,
                                                   int* __restrict__ off) {
    __shared__ int part[256];
    const int t = threadIdx.x;
    const int base = t * 64;
    int s = 0;
#pragma unroll 4
    for (int j = 0; j < 64; ++j) s += cnt[base + j];
    part[t] = s;
    __syncthreads();
    for (int d = 1; d < 256; d <<= 1) {
        int v = (t >= d) ? part[t - d] : 0;
        __syncthreads();
        part[t] += v;
        __syncthreads();
    }
    int run = (t == 0) ? 0 : part[t - 1];
    for (int j = 0; j < 64; ++j) {
        off[base + j] = run;
        run += cnt[base + j];
    }
    if (t == 255) off[NN] = run;
}

__global__ __launch_bounds__(256) void fill_kernel(const int* __restrict__ ei,
                                                   const int* __restrict__ off,
                                                   int* __restrict__ cur,
                                                   const float* __restrict__ dis,
                                                   int* __restrict__ srcs,
                                                   float* __restrict__ wgt, int E) {
    int e = blockIdx.x * blockDim.x + threadIdx.x;
    if (e >= E) return;
    int r = ei[e], c = ei[E + e];
    int pos = off[c] + atomicAdd(&cur[c], 1);
    srcs[pos] = r;
    wgt[pos] = dis[r];
}

// ---------------- hi/lo bf16 conversions (segmented+swizzled layout) ----------------
// Row layout, K feats: K/64 segments x 128 ush; seg = [8 hi chunks | 8 lo chunks],
// chunk of 8 feats, stored chunk = c ^ (row & 7).
__global__ __launch_bounds__(256) void conv_x_kernel(const float* __restrict__ x,
                                                     ushort* __restrict__ xhl) {
    const int t = blockIdx.x * 256 + threadIdx.x;   // NN*64
    const int r = t >> 6, ci = t & 63;
    const int seg = ci >> 3, c = ci & 7;
    const float* src = x + (size_t)r * FIN + ci * 8;
    U8 hi, lo;
#pragma unroll
    for (int u = 0; u < 8; ++u) {
        float v = src[u];
        ushort h = f2bf(v);
        hi.u[u] = h;
        lo.u[u] = f2bf(v - bf2f(h));
    }
    ushort* dst = xhl + (size_t)r * (FIN * 2) + seg * 128 + ((c ^ (r & 7)) * 8);
    *(uint4*)dst = hi.v;
    *(uint4*)(dst + 64) = lo.v;
}

// W^T hi/lo: out row n = column n of W (Kfeat x 256). Wb!=null => [W1|W2] split.
__global__ __launch_bounds__(256) void conv_w_kernel(const float* __restrict__ Wa,
                                                     const float* __restrict__ Wb,
                                                     ushort* __restrict__ whl,
                                                     int Kfeat, int cshift) {
    const int t = blockIdx.x * 256 + threadIdx.x;   // 256 * Kfeat/8
    const int n = t >> cshift, ci = t & ((1 << cshift) - 1);
    const int seg = ci >> 3, c = ci & 7;
    U8 hi, lo;
#pragma unroll
    for (int u = 0; u < 8; ++u) {
        int k = ci * 8 + u;
        float v;
        if (Wb) v = (n < HD2) ? Wa[(size_t)k * HD2 + n] : Wb[(size_t)k * HD2 + (n - HD2)];
        else    v = Wa[(size_t)k * HD + n];
        ushort h = f2bf(v);
        hi.u[u] = h;
        lo.u[u] = f2bf(v - bf2f(h));
    }
    ushort* dst = whl + (size_t)n * (Kfeat * 2) + seg * 128 + ((c ^ (n & 7)) * 8);
    *(uint4*)dst = hi.v;
    *(uint4*)(dst + 64) = lo.v;
}

// ---------------- generic hi/lo GEMM: C[M][256] f32 = Ahl[M][K] . Bhl[256][K]^T ----------------
// 128x128 tile, 4 waves 2x2, 64 KiB LDS (one 64-feat segment), 2 blocks/CU.
__global__ __launch_bounds__(256, 2) void hl_gemm_kernel(const ushort* __restrict__ A,
                                                         const ushort* __restrict__ B,
                                                         float* __restrict__ C,
                                                         int nseg) {
    __shared__ ushort Ash[128 * 128];
    __shared__ ushort Bsh[128 * 128];
    const int tid = threadIdx.x;
    const int lane = tid & 63, wid = tid >> 6;
    const int rA0 = blockIdx.y * 128, cB0 = blockIdx.x * 128;
    const int rowush = nseg * 128;
    const int wm = (wid >> 1) * 64, wn = (wid & 1) * 64;
    const int fr = lane & 15, g = lane >> 4;

    ffrag acc[4][4];
#pragma unroll
    for (int i = 0; i < 4; ++i)
#pragma unroll
        for (int j = 0; j < 4; ++j) acc[i][j] = (ffrag){0.f, 0.f, 0.f, 0.f};

    for (int s = 0; s < nseg; ++s) {
        if (s) __syncthreads();
#pragma unroll
        for (int it = 0; it < 8; ++it) {
            int idx = it * 256 + tid;
            int row = idx >> 4, c16 = idx & 15;
            *(uint4*)&Ash[idx * 8] = *(const uint4*)&A[(size_t)(rA0 + row) * rowush + s * 128 + c16 * 8];
            *(uint4*)&Bsh[idx * 8] = *(const uint4*)&B[(size_t)(cB0 + row) * rowush + s * 128 + c16 * 8];
        }
        __syncthreads();
#pragma unroll
        for (int m = 0; m < 2; ++m) {
            bfrag ah[4], al[4], bh[4], bl[4];
            const int sw = ((m * 4 + g) ^ (fr & 7)) * 8;
#pragma unroll
            for (int mf = 0; mf < 4; ++mf) {
                const int base = (wm + mf * 16 + fr) * 128;
                ah[mf] = *(const bfrag*)&Ash[base + sw];
                al[mf] = *(const bfrag*)&Ash[base + 64 + sw];
            }
#pragma unroll
            for (int nf = 0; nf < 4; ++nf) {
                const int base = (wn + nf * 16 + fr) * 128;
                bh[nf] = *(const bfrag*)&Bsh[base + sw];
                bl[nf] = *(const bfrag*)&Bsh[base + 64 + sw];
            }
#pragma unroll
            for (int mf = 0; mf < 4; ++mf)
#pragma unroll
                for (int nf = 0; nf < 4; ++nf) {
                    acc[mf][nf] = __builtin_amdgcn_mfma_f32_16x16x32_bf16(ah[mf], bh[nf], acc[mf][nf], 0, 0, 0);
                    acc[mf][nf] = __builtin_amdgcn_mfma_f32_16x16x32_bf16(ah[mf], bl[nf], acc[mf][nf], 0, 0, 0);
                    acc[mf][nf] = __builtin_amdgcn_mfma_f32_16x16x32_bf16(al[mf], bh[nf], acc[mf][nf], 0, 0, 0);
                    acc[mf][nf] = __builtin_amdgcn_mfma_f32_16x16x32_bf16(al[mf], bl[nf], acc[mf][nf], 0, 0, 0);
                }
        }
    }
    const size_t row0 = (size_t)rA0 + wm;
    const int col0 = cB0 + wn;
#pragma unroll
    for (int mf = 0; mf < 4; ++mf)
#pragma unroll
        for (int reg = 0; reg < 4; ++reg) {
            float* outp = C + (row0 + mf * 16 + g * 4 + reg) * HD + col0 + fr;
#pragma unroll
            for (int nf = 0; nf < 4; ++nf) outp[nf * 16] = acc[mf][nf][reg];
        }
}

// ---------------- gather layer 1: relu(bias + norm-agg) -> h_hl (swizzled hi/lo) ----------------
__global__ __launch_bounds__(256) void gather0_kernel(const int* __restrict__ off,
                                                      const int* __restrict__ srcs,
                                                      const float* __restrict__ wgt,
                                                      const float* __restrict__ dis,
                                                      const float* __restrict__ A,
                                                      const float* __restrict__ bias,
                                                      ushort* __restrict__ hhl) {
    const int wave = (blockIdx.x * blockDim.x + threadIdx.x) >> 6;
    const int lane = threadIdx.x & 63;
    if (wave >= NN) return;
    const int i = wave;
    const float di = dis[i];
    const int j = lane * 4;
    float4 acc = *(const float4*)&A[(size_t)i * HD + j];
    acc.x *= di; acc.y *= di; acc.z *= di; acc.w *= di;
    const int k1 = off[i + 1];
    for (int k = off[i]; k < k1; ++k) {
        const int s = srcs[k];
        const float w = wgt[k];
        const float4 v = *(const float4*)&A[(size_t)s * HD + j];
        acc.x += w * v.x; acc.y += w * v.y; acc.z += w * v.z; acc.w += w * v.w;
    }
    const float4 bb = *(const float4*)&bias[j];
    acc.x = fmaxf(acc.x * di + bb.x, 0.f);
    acc.y = fmaxf(acc.y * di + bb.y, 0.f);
    acc.z = fmaxf(acc.z * di + bb.z, 0.f);
    acc.w = fmaxf(acc.w * di + bb.w, 0.f);
    ushort4 hv, lv;
    hv.x = f2bf(acc.x); lv.x = f2bf(acc.x - bf2f(hv.x));
    hv.y = f2bf(acc.y); lv.y = f2bf(acc.y - bf2f(hv.y));
    hv.z = f2bf(acc.z); lv.z = f2bf(acc.z - bf2f(hv.z));
    hv.w = f2bf(acc.w); lv.w = f2bf(acc.w - bf2f(hv.w));
    const int seg = lane >> 4, c = (lane >> 1) & 7, half = (lane & 1) * 4;
    ushort* dst = hhl + (size_t)i * (HD * 2) + seg * 128 + ((c ^ (i & 7)) * 8) + half;
    *(ushort4*)dst = hv;
    *(ushort4*)(dst + 64) = lv;
}

// ---------------- gather layer 2: mu/logvar f32 out + z_hl (swizzled hi/lo) ----------------
__global__ __launch_bounds__(256) void gather1_kernel(const int* __restrict__ off,
                                                      const int* __restrict__ srcs,
                                                      const float* __restrict__ wgt,
                                                      const float* __restrict__ dis,
                                                      const float* __restrict__ A,
                                                      const float* __restrict__ b1,
                                                      const float* __restrict__ b2,
                                                      float* __restrict__ out_mu,
                                                      float* __restrict__ out_lv,
                                                      ushort* __restrict__ zhl) {
    const int wave = (blockIdx.x * blockDim.x + threadIdx.x) >> 6;
    const int lane = threadIdx.x & 63;
    if (wave >= NN) return;
    const int i = wave;
    const float di = dis[i];
    const int j = lane * 4;
    float4 acc = *(const float4*)&A[(size_t)i * HD + j];
    acc.x *= di; acc.y *= di; acc.z *= di; acc.w *= di;
    const int k1 = off[i + 1];
    for (int k = off[i]; k < k1; ++k) {
        const int s = srcs[k];
        const float w = wgt[k];
        const float4 v = *(const float4*)&A[(size_t)s * HD + j];
        acc.x += w * v.x; acc.y += w * v.y; acc.z += w * v.z; acc.w += w * v.w;
    }
    acc.x *= di; acc.y *= di; acc.z *= di; acc.w *= di;
    if (lane < 32) {
        const float4 bb = *(const float4*)&b1[j];
        acc.x += bb.x; acc.y += bb.y; acc.z += bb.z; acc.w += bb.w;
        *(float4*)&out_mu[(size_t)i * HD2 + j] = acc;
        ushort4 hv, lv;
        hv.x = f2bf(acc.x); lv.x = f2bf(acc.x - bf2f(hv.x));
        hv.y = f2bf(acc.y); lv.y = f2bf(acc.y - bf2f(hv.y));
        hv.z = f2bf(acc.z); lv.z = f2bf(acc.z - bf2f(hv.z));
        hv.w = f2bf(acc.w); lv.w = f2bf(acc.w - bf2f(hv.w));
        const int seg = lane >> 4, c = (lane >> 1) & 7, half = (lane & 1) * 4;
        ushort* dst = zhl + (size_t)i * (HD2 * 2) + seg * 128 + ((c ^ (i & 7)) * 8) + half;
        *(ushort4*)dst = hv;
        *(ushort4*)(dst + 64) = lv;
    } else {
        const int jj = j - HD2;
        const float4 bb = *(const float4*)&b2[jj];
        acc.x += bb.x; acc.y += bb.y; acc.z += bb.z; acc.w += bb.w;
        *(float4*)&out_lv[(size_t)i * HD2 + jj] = acc;
    }
}

// ---------------- Adj = z z^T, triangular grid + mirror store ----------------
__global__ __launch_bounds__(256, 2) void zz_tri_kernel(const ushort* __restrict__ Z,
                                                        float* __restrict__ adj) {
    const int bm = blockIdx.y, bn = blockIdx.x;
    if (bn < bm) return;  // upper triangle only
    __shared__ ushort Ash[128 * 128];
    __shared__ ushort Bsh[128 * 128];
    const int tid = threadIdx.x;
    const int lane = tid & 63, wid = tid >> 6;
    const int wm = (wid >> 1) * 64, wn = (wid & 1) * 64;
    const int fr = lane & 15, g = lane >> 4;

    ffrag acc[4][4];
#pragma unroll
    for (int i = 0; i < 4; ++i)
#pragma unroll
        for (int j = 0; j < 4; ++j) acc[i][j] = (ffrag){0.f, 0.f, 0.f, 0.f};

#pragma unroll
    for (int s = 0; s < 2; ++s) {
        if (s) __syncthreads();
#pragma unroll
        for (int it = 0; it < 8; ++it) {
            int idx = it * 256 + tid;
            int row = idx >> 4, c16 = idx & 15;
            *(uint4*)&Ash[idx * 8] = *(const uint4*)&Z[(size_t)(bm * 128 + row) * 256 + s * 128 + c16 * 8];
            *(uint4*)&Bsh[idx * 8] = *(const uint4*)&Z[(size_t)(bn * 128 + row) * 256 + s * 128 + c16 * 8];
        }
        __syncthreads();
#pragma unroll
        for (int m = 0; m < 2; ++m) {
            bfrag ah[4], al[4], bh[4], bl[4];
            const int sw = ((m * 4 + g) ^ (fr & 7)) * 8;
#pragma unroll
            for (int mf = 0; mf < 4; ++mf) {
                const int base = (wm + mf * 16 + fr) * 128;
                ah[mf] = *(const bfrag*)&Ash[base + sw];
                al[mf] = *(const bfrag*)&Ash[base + 64 + sw];
            }
#pragma unroll
            for (int nf = 0; nf < 4; ++nf) {
                const int base = (wn + nf * 16 + fr) * 128;
                bh[nf] = *(const bfrag*)&Bsh[base + sw];
                bl[nf] = *(const bfrag*)&Bsh[base + 64 + sw];
            }
#pragma unroll
            for (int mf = 0; mf < 4; ++mf)
#pragma unroll
                for (int nf = 0; nf < 4; ++nf) {
                    acc[mf][nf] = __builtin_amdgcn_mfma_f32_16x16x32_bf16(ah[mf], bh[nf], acc[mf][nf], 0, 0, 0);
                    acc[mf][nf] = __builtin_amdgcn_mfma_f32_16x16x32_bf16(ah[mf], bl[nf], acc[mf][nf], 0, 0, 0);
                    acc[mf][nf] = __builtin_amdgcn_mfma_f32_16x16x32_bf16(al[mf], bh[nf], acc[mf][nf], 0, 0, 0);
                    acc[mf][nf] = __builtin_amdgcn_mfma_f32_16x16x32_bf16(al[mf], bl[nf], acc[mf][nf], 0, 0, 0);
                }
        }
    }

    // normal store (upper tile)
    const size_t row0 = (size_t)bm * 128 + wm;
    const int col0 = bn * 128 + wn;
#pragma unroll
    for (int mf = 0; mf < 4; ++mf)
#pragma unroll
        for (int reg = 0; reg < 4; ++reg) {
            float* outp = adj + (row0 + mf * 16 + g * 4 + reg) * NN + col0 + fr;
#pragma unroll
            for (int nf = 0; nf < 4; ++nf) outp[nf * 16] = acc[mf][nf][reg];
        }
    // mirror store (lower tile): Adj[c][r] = Adj[r][c]; the 4 regs are 4 consecutive cols
    if (bm != bn) {
#pragma unroll
        for (int nf = 0; nf < 4; ++nf)
#pragma unroll
            for (int mf = 0; mf < 4; ++mf) {
                const size_t addr = ((size_t)bn * 128 + wn + nf * 16 + fr) * NN
                                  + (size_t)bm * 128 + wm + mf * 16 + g * 4;
                *(float4*)&adj[addr] = *(float4*)&acc[mf][nf];
            }
    }
}

extern "C" void kernel_launch(void* const* d_in, const int* in_sizes, int n_in,
                              void* d_out, int out_size, void* d_ws, size_t ws_size,
                              hipStream_t stream) {
    const float* x     = (const float*)d_in[0];
    const int*   ei    = (const int*)d_in[1];
    const float* W_enc = (const float*)d_in[2];
    const float* b_enc = (const float*)d_in[3];
    const float* W1    = (const float*)d_in[4];
    const float* b1    = (const float*)d_in[5];
    const float* W2    = (const float*)d_in[6];
    const float* b2    = (const float*)d_in[7];

    float* out    = (float*)d_out;
    float* adj    = out;
    float* out_mu = out + (size_t)NN * NN;
    float* out_lv = out_mu + (size_t)NN * HD2;

    float*  ws    = (float*)d_ws;
    float*  dis   = ws;                                  // NN f32
    float*  bufA  = ws + NN;                             // NN*HD f32 (C1 then C2)
    ushort* xhl   = (ushort*)(bufA + (size_t)NN * HD);   // NN*1024 ush (33.5 MB)
    ushort* hhl   = xhl;                                 // reuse after gemm1 (NN*512 ush)
    ushort* zhl   = xhl + (size_t)NN * 512;              // reuse tail (NN*256 ush)
    ushort* wencT = xhl + (size_t)NN * 1024;             // 256*1024 ush
    ushort* wcatT = wencT + 256 * 1024;                  // 256*512 ush
    float*  wgt   = (float*)(wcatT + 256 * 512);         // NE f32
    int*    icnt  = (int*)(wgt + NE);                    // NN
    int*    off   = icnt + NN;                           // NN+1
    int*    cur   = off + NN + 1;                        // NN
    int*    srcs  = cur + NN;                            // NE

    // CSR build
    hipMemsetAsync(icnt, 0, NN * sizeof(int), stream);
    hipMemsetAsync(cur, 0, NN * sizeof(int), stream);
    count_deg_kernel<<<NE / 256, 256, 0, stream>>>(ei + NE, icnt, NE);
    finish_dis_kernel<<<NN / 256, 256, 0, stream>>>(icnt, dis, NN);
    scan_kernel<<<1, 256, 0, stream>>>(icnt, off);
    fill_kernel<<<NE / 256, 256, 0, stream>>>(ei, off, cur, dis, srcs, wgt, NE);

    // hi/lo conversions
    conv_x_kernel<<<NN * 64 / 256, 256, 0, stream>>>(x, xhl);
    conv_w_kernel<<<64, 256, 0, stream>>>(W_enc, nullptr, wencT, FIN, 6);
    conv_w_kernel<<<32, 256, 0, stream>>>(W1, W2, wcatT, HD, 5);

    // layer 1: XW (MFMA) -> gather+relu -> h_hl
    hl_gemm_kernel<<<dim3(2, NN / 128), 256, 0, stream>>>(xhl, wencT, bufA, FIN / 64);
    gather0_kernel<<<NN * 64 / 256, 256, 0, stream>>>(off, srcs, wgt, dis, bufA, b_enc, hhl);

    // layer 2: HW (MFMA) -> gather -> mu/logvar + z_hl
    hl_gemm_kernel<<<dim3(2, NN / 128), 256, 0, stream>>>(hhl, wcatT, bufA, HD / 64);
    gather1_kernel<<<NN * 64 / 256, 256, 0, stream>>>(off, srcs, wgt, dis, bufA, b1, b2,
                                                      out_mu, out_lv, zhl);

    // Adj = z z^T (triangular + mirror)
    zz_tri_kernel<<<dim3(NN / 128, NN / 128), 256, 0, stream>>>(zhl, adj);
}